// Round 12
// baseline (26.811 us; speedup 1.0000x reference)
//
#include <hip/hip_runtime.h>
#include <math.h>

// KDE Gaussian, bandwidth 0.1 — separable reformulation, 2-dispatch graph.
//   exp(-50*((x-sx)^2+(y-sy)^2)) = fx(i)*fy(j)  =>  out_b = Fx_b^T * Fy_b.
// kde_gemm: 256 blocks = (batch, K-chunk of 64), 256 thr — ALL 256 CUs.
//   8x8 thread-tile => 2.0 FLOP per LDS byte (chip LDS floor ~3.4us).
//   fy stored via sgm() slot swizzle: ya/yb reads are 2-way banked (free,
//   m136); fx reads are 4-address broadcasts (conflict-free). 16K exps per
//   block, each table entry computed exactly once chip-wide.
//   Private 64 KB partial slice per block, plain float4 stores (R9 lesson:
//   global fp32 atomics cost ~32B RMW traffic each — never for dense acc).
// kde_fin: 128 blocks x 128 thr, sum 64 slices + scale by 1/norm.
//   norm_b analytic (validated R8-R11): sum_n S(x_n)S(y_n),
//   S(u) = K2*(erf(AE-sq50 u)+erf(AE+sq50 u)).  No memsets, no atomics.

#define W_CONST (-72.13475204444817f)   // -50 * log2(e)
#define SQ50    7.07106781f             // sqrt(50)
#define AE      21.3802390f             // sqrt(50)*(3 + h/2)
#define K2      2.65284825f             // (127/6)*0.5*sqrt(pi/50)

constexpr int Bc = 4, Nc = 4096, Mc = 128 * 128;
constexpr int KC = 64;                  // samples per chunk
constexpr int NCHK = Nc / KC;           // 64 chunks/batch -> 64 slices
constexpr float Hh = 6.0f / 127.0f;     // grid spacing

typedef float f2 __attribute__((ext_vector_type(2)));

__device__ __forceinline__ float fexp2(float x) {
#if __has_builtin(__builtin_amdgcn_exp2f)
    return __builtin_amdgcn_exp2f(x);        // raw v_exp_f32
#else
    float r; asm("v_exp_f32 %0, %1" : "=v"(r) : "v"(x)); return r;
#endif
}
__device__ __forceinline__ f2 pkfma(f2 a, f2 b, f2 c) {
    return __builtin_elementwise_fma(a, b, c);   // v_pk_fma_f32
}
// fy slot swizzle: even float4-slots -> 0..15, odd -> 16..31.  Read sets
// {2v}->{v} and {2v+1}->{16+v}: banks 4v%32, v and v+8 collide = 2-way (free).
__device__ __forceinline__ int sgm(int fq) {
    return (fq >> 1) | ((fq & 1) << 4);
}

__global__ __launch_bounds__(256) void kde_gemm(
        const float2* __restrict__ samples, float* __restrict__ partial,
        float* __restrict__ normp) {
    __shared__ float2 smp[KC];          //  0.5 KB
    __shared__ float4 fx4[KC][32];      //   32 KB
    __shared__ float4 fy4[KC][32];      //   32 KB

    const int bid = blockIdx.x;
    const int b = bid >> 6, kc = bid & 63;
    const int tid = threadIdx.x;

    if (tid < KC) smp[tid] = samples[b * Nc + kc * KC + tid];
    __syncthreads();

    // Build tables: 64 samples x 32 float4-slots x {fx,fy}; 8 pairs/thread.
#pragma unroll
    for (int r = 0; r < 8; ++r) {
        const int idx = r * 256 + tid;       // 0..2047
        const int n = idx >> 5, fq = idx & 31, i0 = fq << 2;
        const float2 s = smp[n];             // LDS broadcast
        float4 vx, vy;
#pragma unroll
        for (int k = 0; k < 4; ++k) {
            const float xi = -3.0f + (float)(i0 + k) * Hh;
            const float dx = xi - s.x, dy = xi - s.y;
            ((float*)&vx)[k] = fexp2(W_CONST * dx * dx);
            ((float*)&vy)[k] = fexp2(W_CONST * dy * dy);
        }
        fx4[n][fq] = vx;                     // 2-way write banks (free)
        fy4[n][sgm(fq)] = vy;                // swizzled store, 2-way (free)
    }

    // Analytic normalizer partial for this chunk (wave 0; plain store).
    if (tid < 64) {
        const float2 s = smp[tid];
        const float sx = K2 * (erff(AE - SQ50 * s.x) + erff(AE + SQ50 * s.x));
        const float sy = K2 * (erff(AE - SQ50 * s.y) + erff(AE + SQ50 * s.y));
        float p = sx * sy;
#pragma unroll
        for (int off = 32; off > 0; off >>= 1) p += __shfl_down(p, off, 64);
        if (tid == 0) normp[bid] = p;
    }
    __syncthreads();

    // GEMM: thread = 8x8 tile. u,v in 0..15; R=u*8 rows, C=v*8 cols.
    const int u = tid >> 4, v = tid & 15;
    f2 acc[8][4];
#pragma unroll
    for (int r = 0; r < 8; ++r)
#pragma unroll
        for (int c = 0; c < 4; ++c) acc[r][c] = (f2)(0.0f);

#pragma unroll 4
    for (int n = 0; n < KC; ++n) {
        const float4 fxa = fx4[n][2 * u];        // 4-addr broadcast, clean
        const float4 fxb = fx4[n][2 * u + 1];
        const float4 ya  = fy4[n][v];            // 2-way banks (free)
        const float4 yb  = fy4[n][16 + v];       // 2-way banks (free)
        const f2 y0 = {ya.x, ya.y}, y1 = {ya.z, ya.w};
        const f2 y2 = {yb.x, yb.y}, y3 = {yb.z, yb.w};
        const float xr[8] = {fxa.x, fxa.y, fxa.z, fxa.w,
                             fxb.x, fxb.y, fxb.z, fxb.w};
#pragma unroll
        for (int r = 0; r < 8; ++r) {            // compile-time indices
            const f2 x = (f2)(xr[r]);
            acc[r][0] = pkfma(x, y0, acc[r][0]);
            acc[r][1] = pkfma(x, y1, acc[r][1]);
            acc[r][2] = pkfma(x, y2, acc[r][2]);
            acc[r][3] = pkfma(x, y3, acc[r][3]);
        }
    }

    // Plain coalesced stores into this block's private slice.
    float* P = partial + (size_t)bid * Mc;
    const int R = u * 8, C = v * 8;
#pragma unroll
    for (int r = 0; r < 8; ++r) {
        float* row = P + (R + r) * 128 + C;
        *(float4*)(row)     = make_float4(acc[r][0].x, acc[r][0].y,
                                          acc[r][1].x, acc[r][1].y);
        *(float4*)(row + 4) = make_float4(acc[r][2].x, acc[r][2].y,
                                          acc[r][3].x, acc[r][3].y);
    }
}

__global__ __launch_bounds__(128) void kde_fin(
        const float4* __restrict__ partial4, const float* __restrict__ normp,
        float4* __restrict__ out4) {
    const int f = blockIdx.x * 128 + threadIdx.x;   // 0..16383 (Bc*Mc/4)
    const int b = f >> 12, col = f & 4095;
    float nsum = 0.f;
#pragma unroll
    for (int s = 0; s < NCHK; ++s) nsum += normp[b * NCHK + s];  // uniform
    const float inv = 1.0f / nsum;
    float sx = 0.f, sy = 0.f, sz = 0.f, sw = 0.f;
#pragma unroll 8
    for (int s = 0; s < NCHK; ++s) {
        const float4 v = partial4[(size_t)(b * NCHK + s) * 4096 + col];
        sx += v.x; sy += v.y; sz += v.z; sw += v.w;
    }
    out4[f] = make_float4(sx * inv, sy * inv, sz * inv, sw * inv);
}

extern "C" void kernel_launch(void* const* d_in, const int* in_sizes, int n_in,
                              void* d_out, int out_size, void* d_ws, size_t ws_size,
                              hipStream_t stream) {
    const float* samples = (const float*)d_in[0];   // (B, N, 2) fp32
    float* out = (float*)d_out;                     // (B, H, W) fp32

    char* ws = (char*)d_ws;
    float* partial = (float*)ws;                    // 256 slices * 64 KB = 16 MB
    float* normp   = (float*)(ws + (size_t)16777216);  // 256 floats

    kde_gemm<<<Bc * NCHK, 256, 0, stream>>>((const float2*)samples,
                                            partial, normp);
    kde_fin <<<Bc * Mc / 4 / 128, 128, 0, stream>>>((const float4*)partial,
                                                    normp, (float4*)out);
}